// Round 17
// baseline (374.720 us; speedup 1.0000x reference)
//
#include <hip/hip_runtime.h>
#include <hip/hip_fp16.h>
#include <hip/hip_cooperative_groups.h>

namespace cg = cooperative_groups;

#define N_NODES 131072
#define N_EDGES 4194304
#define NUM_GRAPHS 128

#define NB 512        // buckets (write-locality-friendly binning)
#define NPB 256       // nodes per bucket
#define BSHIFT 8      // dst>>8 = bucket, dst&255 = local node
#define BCAP 10240    // slots per bucket (mean 8192, sd ~90 -> +22 sigma)
#define GSPAN 8       // max graphs tracked in LDS per bucket (fallback: global)

typedef int iv4 __attribute__((ext_vector_type(4)));  // NT-loadable int4

// ------- bin edges by dst bucket; batch-reserved contiguous runs ---------------
__global__ __launch_bounds__(1024) void k_binfill(const iv4* __restrict__ src4,
                                                  const iv4* __restrict__ dst4,
                                                  int* __restrict__ bcount,
                                                  unsigned* __restrict__ binned) {
  __shared__ int base_[NB], rank_[NB];
  for (int k = threadIdx.x; k < NB; k += 1024) rank_[k] = 0;
  __syncthreads();
  unsigned pk[16];
  int bk[16], rr[16];
  int q0 = blockIdx.x * 4096 + threadIdx.x;  // int4 index
  #pragma unroll
  for (int i = 0; i < 4; ++i) {
    iv4 sv = __builtin_nontemporal_load(&src4[q0 + i * 1024]);
    iv4 dv = __builtin_nontemporal_load(&dst4[q0 + i * 1024]);
    #pragma unroll
    for (int j = 0; j < 4; ++j) {
      int idx = i * 4 + j;
      int s = sv[j], d = dv[j];
      bk[idx] = d >> BSHIFT;
      pk[idx] = ((unsigned)s << BSHIFT) | (unsigned)(d & (NPB - 1));
      rr[idx] = atomicAdd(&rank_[bk[idx]], 1);
    }
  }
  __syncthreads();
  for (int k = threadIdx.x; k < NB; k += 1024)
    base_[k] = k * BCAP + atomicAdd(&bcount[k], rank_[k]);
  __syncthreads();
  #pragma unroll
  for (int i = 0; i < 16; ++i)
    binned[base_[bk[i]] + rr[i]] = pk[i];   // plain store: L2 merges the scatter
}

// ---- fused cooperative (512 thr): sort once | xs | sync | conv1 | sync | conv2+pool
__global__ __launch_bounds__(512, 4) void k_fused(const unsigned* __restrict__ binned,
                                                  const int* __restrict__ bcount,
                                                  const float* __restrict__ x,
                                                  const int* __restrict__ batch,
                                                  const float* __restrict__ W1,
                                                  const float* __restrict__ b1,
                                                  const float* __restrict__ W2,
                                                  const float* __restrict__ b2,
                                                  float4* __restrict__ xs4,
                                                  unsigned* __restrict__ h1h,
                                                  float* __restrict__ gsum) {
  __shared__ int csrL[BCAP];          // 40 KB; phase3 overlays aggS here
  __shared__ int dcount[NPB], cursor[NPB], nbase[NPB];
  __shared__ int wsum[4];
  __shared__ float w1s[48], b1s[16];
  __shared__ float w2s[1024], b2s[64];
  __shared__ float gacc[GSPAN * 64];
  __shared__ float accS[NPB * 4];

  int tid = threadIdx.x;
  int b = blockIdx.x;

  w2s[tid] = W2[tid];
  w2s[tid + 512] = W2[tid + 512];
  if (tid < 48) w1s[tid] = W1[tid];
  if (tid >= 64 && tid < 80) b1s[tid - 64] = b1[tid - 64];
  if (tid >= 128 && tid < 192) b2s[tid - 128] = b2[tid - 128];
  gacc[tid] = 0.f;                      // GSPAN*64 == 512
  if (tid < NPB) dcount[tid] = 0;
  __syncthreads();

  // ---- counting sort into csrL -------------------------------------------------
  int s0 = b * BCAP;
  int n = bcount[b];
  unsigned ent_r[20];
  #pragma unroll
  for (int j = 0; j < 20; ++j) {
    int e = tid + j * 512;
    if (e < n) {
      unsigned ent = __builtin_nontemporal_load(&binned[s0 + e]);
      ent_r[j] = ent;
      atomicAdd(&dcount[ent & (NPB - 1)], 1);
    }
  }
  __syncthreads();

  int v = (tid < NPB) ? dcount[tid] : 0;
  {
    int incl = v;
    #pragma unroll
    for (int d = 1; d < 64; d <<= 1) {
      int t = __shfl_up(incl, d);
      if ((tid & 63) >= d) incl += t;
    }
    if (tid < NPB && (tid & 63) == 63) wsum[tid >> 6] = incl;
    __syncthreads();
    if (tid < NPB) {
      int base = 0;
      int wv = tid >> 6;
      for (int w2 = 0; w2 < wv; ++w2) base += wsum[w2];
      int pref = base + incl - v;
      cursor[tid] = pref;
      nbase[tid] = pref;
    }
  }
  __syncthreads();

  #pragma unroll
  for (int j = 0; j < 20; ++j) {
    int e = tid + j * 512;
    if (e < n) {
      unsigned ent = ent_r[j];
      int pos = atomicAdd(&cursor[ent & (NPB - 1)], 1);
      csrL[pos] = (int)(ent >> BSHIFT) << 4;  // byte offset into xs4 rows
    }
  }

  // ---- phase 1: xs = dinv * x ---------------------------------------------------
  if (tid < NPB) {
    int node = b * NPB + tid;
    float di = rsqrtf((float)(dcount[tid] + 1));  // +1: self-loop
    xs4[node] = make_float4(di * x[node * 3 + 0], di * x[node * 3 + 1],
                            di * x[node * 3 + 2], 0.f);
  }
  __threadfence();
  cg::this_grid().sync();

  // ---- phase 2: gather xs + W1 proj + relu -> h1h (fp16) -------------------------
  {
    const char* xsc = (const char*)xs4;
    int q = tid & 3;
    int qb = q << 2;
    int dl0 = tid >> 2;  // 0..127
    #pragma unroll
    for (int pass = 0; pass < 2; ++pass) {
      int dl = dl0 + pass * 128;
      int off = nbase[dl], len = dcount[dl];
      float acc = 0.f;
      #pragma unroll 4
      for (int k = 0; k < len; ++k) {
        int bo = csrL[off + k];
        acc += *(const float*)(xsc + bo + qb);
      }
      accS[dl * 4 + q] = acc;
    }
    __syncthreads();
    #pragma unroll
    for (int pass = 0; pass < 2; ++pass) {
      int dl = dl0 + pass * 128;
      int node = b * NPB + dl;
      int len = dcount[dl];
      float di = rsqrtf((float)(len + 1));
      float4 xself = xs4[node];
      float a0 = di * (accS[dl * 4 + 0] + xself.x);
      float a1 = di * (accS[dl * 4 + 1] + xself.y);
      float a2 = di * (accS[dl * 4 + 2] + xself.z);
      float o[4];
      #pragma unroll
      for (int j = 0; j < 4; ++j) {
        int cc = q * 4 + j;
        float vv = a0 * w1s[cc] + a1 * w1s[16 + cc] + a2 * w1s[32 + cc] + b1s[cc];
        o[j] = di * fmaxf(vv, 0.f);
      }
      __half2 p0 = __floats2half2_rn(o[0], o[1]);
      __half2 p1 = __floats2half2_rn(o[2], o[3]);
      uint2 st;
      st.x = *reinterpret_cast<unsigned*>(&p0);
      st.y = *reinterpret_cast<unsigned*>(&p1);
      *(uint2*)(h1h + (size_t)node * 8 + q * 2) = st;
    }
  }
  __threadfence();
  cg::this_grid().sync();

  // ---- phase 3: gather h1 (f32 acc) + W2 proj + graph pool -----------------------
  {
    const char* h1c = (const char*)h1h;
    int q = tid & 3;
    int qb = q << 3;
    int dl0 = tid >> 2;
    float pa0, pa1, pa2, pa3, qa0, qa1, qa2, qa3;
    {  // pass 0: node dl0
      int node = b * NPB + dl0;
      int off = nbase[dl0], len = dcount[dl0];
      float o0 = 0.f, o1 = 0.f, o2 = 0.f, o3 = 0.f;
      #pragma unroll 4
      for (int k = 0; k < len; ++k) {
        int bo = csrL[off + k] << 1;                 // srcn<<5: 32B h1h rows
        uint2 hv = *(const uint2*)(h1c + bo + qb);
        __half2 p0 = *reinterpret_cast<const __half2*>(&hv.x);
        __half2 p1 = *reinterpret_cast<const __half2*>(&hv.y);
        o0 += __low2float(p0); o1 += __high2float(p0);
        o2 += __low2float(p1); o3 += __high2float(p1);
      }
      float di = rsqrtf((float)(len + 1));
      uint2 sv = *(const uint2*)(h1h + (size_t)node * 8 + q * 2);
      __half2 s0h = *reinterpret_cast<const __half2*>(&sv.x);
      __half2 s1h = *reinterpret_cast<const __half2*>(&sv.y);
      pa0 = di * (o0 + __low2float(s0h));
      pa1 = di * (o1 + __high2float(s0h));
      pa2 = di * (o2 + __low2float(s1h));
      pa3 = di * (o3 + __high2float(s1h));
    }
    {  // pass 1: node dl0+128
      int dl = dl0 + 128;
      int node = b * NPB + dl;
      int off = nbase[dl], len = dcount[dl];
      float o0 = 0.f, o1 = 0.f, o2 = 0.f, o3 = 0.f;
      #pragma unroll 4
      for (int k = 0; k < len; ++k) {
        int bo = csrL[off + k] << 1;
        uint2 hv = *(const uint2*)(h1c + bo + qb);
        __half2 p0 = *reinterpret_cast<const __half2*>(&hv.x);
        __half2 p1 = *reinterpret_cast<const __half2*>(&hv.y);
        o0 += __low2float(p0); o1 += __high2float(p0);
        o2 += __low2float(p1); o3 += __high2float(p1);
      }
      float di = rsqrtf((float)(len + 1));
      uint2 sv = *(const uint2*)(h1h + (size_t)node * 8 + q * 2);
      __half2 s0h = *reinterpret_cast<const __half2*>(&sv.x);
      __half2 s1h = *reinterpret_cast<const __half2*>(&sv.y);
      qa0 = di * (o0 + __low2float(s0h));
      qa1 = di * (o1 + __high2float(s0h));
      qa2 = di * (o2 + __low2float(s1h));
      qa3 = di * (o3 + __high2float(s1h));
    }
    __syncthreads();                 // all csrL reads done -> overlay aggS
    float* aggS = (float*)csrL;      // 16 KB within the 40 KB region
    aggS[dl0 * 16 + q * 4 + 0] = pa0;
    aggS[dl0 * 16 + q * 4 + 1] = pa1;
    aggS[dl0 * 16 + q * 4 + 2] = pa2;
    aggS[dl0 * 16 + q * 4 + 3] = pa3;
    int dl1 = dl0 + 128;
    aggS[dl1 * 16 + q * 4 + 0] = qa0;
    aggS[dl1 * 16 + q * 4 + 1] = qa1;
    aggS[dl1 * 16 + q * 4 + 2] = qa2;
    aggS[dl1 * 16 + q * 4 + 3] = qa3;
    __syncthreads();

    // h2 = relu(agg @ W2 + b2), pooled by graph (wave-uniform node), 8 waves
    int c = tid & 63;
    int slot = tid >> 6;
    int g0 = batch[b * NPB];
    float racc = 0.f;
    int curli = -1;
    for (int nloc = slot; nloc < NPB; nloc += 8) {
      int li = batch[b * NPB + nloc] - g0;
      if (li != curli) {
        if (curli >= 0) {
          if (curli < GSPAN) atomicAdd(&gacc[curli * 64 + c], racc);
          else atomicAdd(&gsum[(size_t)(g0 + curli) * 64 + c], racc);
        }
        curli = li;
        racc = 0.f;
      }
      float vv = b2s[c];
      const float* ar = &aggS[nloc * 16];
      #pragma unroll
      for (int k = 0; k < 16; ++k) vv += ar[k] * w2s[k * 64 + c];
      racc += fmaxf(vv, 0.f);
    }
    if (curli >= 0) {
      if (curli < GSPAN) atomicAdd(&gacc[curli * 64 + c], racc);
      else atomicAdd(&gsum[(size_t)(g0 + curli) * 64 + c], racc);
    }
    __syncthreads();

    int span = batch[b * NPB + NPB - 1] - g0 + 1;
    if (span > GSPAN) span = GSPAN;
    for (int li = tid >> 6; li < span; li += 8)
      atomicAdd(&gsum[(size_t)(g0 + li) * 64 + c], gacc[li * 64 + c]);
  }
}

// ================= fallback split pipeline (proven ~120 us, absmax 0) ==========

__global__ __launch_bounds__(1024) void k_prep(const unsigned* __restrict__ binned,
                                               const int* __restrict__ bcount,
                                               const float* __restrict__ x,
                                               float4* __restrict__ xs4) {
  __shared__ int dcount[NPB];
  int tid = threadIdx.x;
  if (tid < NPB) dcount[tid] = 0;
  __syncthreads();
  int b = blockIdx.x;
  int s0 = b * BCAP;
  int n = bcount[b];
  for (int e = tid; e < n; e += 1024) {
    unsigned ent = __builtin_nontemporal_load(&binned[s0 + e]);
    atomicAdd(&dcount[ent & (NPB - 1)], 1);
  }
  __syncthreads();
  if (tid < NPB) {
    int node = b * NPB + tid;
    float di = rsqrtf((float)(dcount[tid] + 1));
    xs4[node] = make_float4(di * x[node * 3 + 0], di * x[node * 3 + 1],
                            di * x[node * 3 + 2], 0.f);
  }
}

__global__ __launch_bounds__(1024) void k_fb3h1(const unsigned* __restrict__ binned,
                                                const int* __restrict__ bcount,
                                                const float* __restrict__ xs,
                                                const float4* __restrict__ xs4,
                                                const float* __restrict__ W1,
                                                const float* __restrict__ b1,
                                                unsigned* __restrict__ h1h) {
  __shared__ int dcount[NPB], cursor[NPB], nbase[NPB];
  __shared__ int wsum[4];
  __shared__ int csrL[BCAP];
  __shared__ float w[48];
  __shared__ float bb[16];
  __shared__ float accS[NPB * 4];
  int tid = threadIdx.x;
  if (tid >= 512 && tid < 560) w[tid - 512] = W1[tid - 512];
  if (tid >= 576 && tid < 592) bb[tid - 576] = b1[tid - 576];
  if (tid < NPB) dcount[tid] = 0;
  __syncthreads();

  int b = blockIdx.x;
  int s0 = b * BCAP;
  int n = bcount[b];
  unsigned ent_r[10];
  #pragma unroll
  for (int j = 0; j < 10; ++j) {
    int e = tid + j * 1024;
    if (e < n) {
      unsigned ent = __builtin_nontemporal_load(&binned[s0 + e]);
      ent_r[j] = ent;
      atomicAdd(&dcount[ent & (NPB - 1)], 1);
    }
  }
  __syncthreads();

  int v = (tid < NPB) ? dcount[tid] : 0;
  {
    int incl = v;
    #pragma unroll
    for (int d = 1; d < 64; d <<= 1) {
      int t = __shfl_up(incl, d);
      if ((tid & 63) >= d) incl += t;
    }
    if (tid < NPB && (tid & 63) == 63) wsum[tid >> 6] = incl;
    __syncthreads();
    if (tid < NPB) {
      int base = 0;
      int wv = tid >> 6;
      for (int w2 = 0; w2 < wv; ++w2) base += wsum[w2];
      int pref = base + incl - v;
      cursor[tid] = pref;
      nbase[tid] = pref;
    }
  }
  __syncthreads();

  #pragma unroll
  for (int j = 0; j < 10; ++j) {
    int e = tid + j * 1024;
    if (e < n) {
      unsigned ent = ent_r[j];
      int pos = atomicAdd(&cursor[ent & (NPB - 1)], 1);
      csrL[pos] = (int)(ent >> BSHIFT) << 4;
    }
  }
  __syncthreads();

  int dl = tid >> 2;
  int q = tid & 3;
  int node = b * NPB + dl;
  int off = nbase[dl];
  int len = dcount[dl];
  const char* xsc = (const char*)xs;
  int qb = q << 2;
  float acc = 0.f;
  #pragma unroll 4
  for (int k = 0; k < len; ++k) {
    int bo = csrL[off + k];
    acc += *(const float*)(xsc + bo + qb);
  }
  accS[tid] = acc;
  __syncthreads();

  float di = rsqrtf((float)(len + 1));
  float4 xself = xs4[node];
  float a0 = di * (accS[dl * 4 + 0] + xself.x);
  float a1 = di * (accS[dl * 4 + 1] + xself.y);
  float a2 = di * (accS[dl * 4 + 2] + xself.z);
  float o[4];
  #pragma unroll
  for (int j = 0; j < 4; ++j) {
    int cc = q * 4 + j;
    float vv = a0 * w[cc] + a1 * w[16 + cc] + a2 * w[32 + cc] + bb[cc];
    o[j] = di * fmaxf(vv, 0.f);
  }
  __half2 p0 = __floats2half2_rn(o[0], o[1]);
  __half2 p1 = __floats2half2_rn(o[2], o[3]);
  uint2 st;
  st.x = *reinterpret_cast<unsigned*>(&p0);
  st.y = *reinterpret_cast<unsigned*>(&p1);
  *(uint2*)(h1h + (size_t)node * 8 + q * 2) = st;
}

__global__ __launch_bounds__(1024) void k_fb16pool(const unsigned* __restrict__ binned,
                                                   const int* __restrict__ bcount,
                                                   const unsigned* __restrict__ h1h,
                                                   const int* __restrict__ batch,
                                                   const float* __restrict__ W2,
                                                   const float* __restrict__ b2,
                                                   float* __restrict__ gsum) {
  __shared__ int dcount[NPB], cursor[NPB], nbase[NPB];
  __shared__ int wsum[4];
  __shared__ int csrL[BCAP];          // phase B overlays aggS here
  __shared__ float w2s[1024];
  __shared__ float b2s[64];
  __shared__ float gacc[GSPAN * 64];
  int tid = threadIdx.x;
  w2s[tid] = W2[tid];
  if (tid < 64) b2s[tid] = b2[tid];
  if (tid < GSPAN * 64) gacc[tid] = 0.f;
  if (tid < NPB) dcount[tid] = 0;
  __syncthreads();

  int b = blockIdx.x;
  int s0 = b * BCAP;
  int n = bcount[b];
  unsigned ent_r[10];
  #pragma unroll
  for (int j = 0; j < 10; ++j) {
    int e = tid + j * 1024;
    if (e < n) {
      unsigned ent = __builtin_nontemporal_load(&binned[s0 + e]);
      ent_r[j] = ent;
      atomicAdd(&dcount[ent & (NPB - 1)], 1);
    }
  }
  __syncthreads();

  int v = (tid < NPB) ? dcount[tid] : 0;
  {
    int incl = v;
    #pragma unroll
    for (int d = 1; d < 64; d <<= 1) {
      int t = __shfl_up(incl, d);
      if ((tid & 63) >= d) incl += t;
    }
    if (tid < NPB && (tid & 63) == 63) wsum[tid >> 6] = incl;
    __syncthreads();
    if (tid < NPB) {
      int base = 0;
      int wv = tid >> 6;
      for (int w2 = 0; w2 < wv; ++w2) base += wsum[w2];
      int pref = base + incl - v;
      cursor[tid] = pref;
      nbase[tid] = pref;
    }
  }
  __syncthreads();

  #pragma unroll
  for (int j = 0; j < 10; ++j) {
    int e = tid + j * 1024;
    if (e < n) {
      unsigned ent = ent_r[j];
      int pos = atomicAdd(&cursor[ent & (NPB - 1)], 1);
      csrL[pos] = (int)(ent >> BSHIFT) << 5;  // byte offset into h1h rows
    }
  }
  __syncthreads();

  const char* h1c = (const char*)h1h;
  int dl = tid >> 2;
  int q = tid & 3;
  int qb = q << 3;
  int node = b * NPB + dl;
  int off = nbase[dl];
  int len = dcount[dl];
  float o0 = 0.f, o1 = 0.f, o2 = 0.f, o3 = 0.f;
  #pragma unroll 4
  for (int k = 0; k < len; ++k) {
    int bo = csrL[off + k];
    uint2 hv = *(const uint2*)(h1c + bo + qb);
    __half2 p0 = *reinterpret_cast<const __half2*>(&hv.x);
    __half2 p1 = *reinterpret_cast<const __half2*>(&hv.y);
    o0 += __low2float(p0); o1 += __high2float(p0);
    o2 += __low2float(p1); o3 += __high2float(p1);
  }
  float di = rsqrtf((float)(len + 1));
  uint2 sv = *(const uint2*)(h1h + (size_t)node * 8 + q * 2);
  __half2 s0h = *reinterpret_cast<const __half2*>(&sv.x);
  __half2 s1h = *reinterpret_cast<const __half2*>(&sv.y);
  o0 = di * (o0 + __low2float(s0h));
  o1 = di * (o1 + __high2float(s0h));
  o2 = di * (o2 + __low2float(s1h));
  o3 = di * (o3 + __high2float(s1h));
  __syncthreads();                 // all csrL reads done -> overlay aggS
  float* aggS = (float*)csrL;
  aggS[dl * 16 + q * 4 + 0] = o0;
  aggS[dl * 16 + q * 4 + 1] = o1;
  aggS[dl * 16 + q * 4 + 2] = o2;
  aggS[dl * 16 + q * 4 + 3] = o3;
  __syncthreads();

  int c = tid & 63;
  int slot = tid >> 6;  // 16 waves
  int g0 = batch[b * NPB];
  float racc = 0.f;
  int curli = -1;
  for (int nloc = slot; nloc < NPB; nloc += 16) {
    int li = batch[b * NPB + nloc] - g0;
    if (li != curli) {
      if (curli >= 0) {
        if (curli < GSPAN) atomicAdd(&gacc[curli * 64 + c], racc);
        else atomicAdd(&gsum[(size_t)(g0 + curli) * 64 + c], racc);
      }
      curli = li;
      racc = 0.f;
    }
    float vv = b2s[c];
    const float* ar = &aggS[nloc * 16];
    #pragma unroll
    for (int k = 0; k < 16; ++k) vv += ar[k] * w2s[k * 64 + c];
    racc += fmaxf(vv, 0.f);
  }
  if (curli >= 0) {
    if (curli < GSPAN) atomicAdd(&gacc[curli * 64 + c], racc);
    else atomicAdd(&gsum[(size_t)(g0 + curli) * 64 + c], racc);
  }
  __syncthreads();

  int span = batch[b * NPB + NPB - 1] - g0 + 1;
  if (span > GSPAN) span = GSPAN;
  for (int li = tid >> 6; li < span; li += 16)
    atomicAdd(&gsum[(size_t)(g0 + li) * 64 + c], gacc[li * 64 + c]);
}

// ---- final: per-graph mean + FC MLP (64->32->2) --------------------------------
__global__ __launch_bounds__(64) void k_fc(const float* __restrict__ gsum,
                                           const int* __restrict__ batch,
                                           const float* __restrict__ fcw1,
                                           const float* __restrict__ fcb1,
                                           const float* __restrict__ fcw2,
                                           const float* __restrict__ fcb2,
                                           float* __restrict__ out) {
  int g = blockIdx.x;
  int lo = 0, hi = N_NODES;
  while (lo < hi) { int m = (lo + hi) >> 1; if (batch[m] < g) lo = m + 1; else hi = m; }
  int start = lo;
  lo = start; hi = N_NODES;
  while (lo < hi) { int m = (lo + hi) >> 1; if (batch[m] < g + 1) lo = m + 1; else hi = m; }
  float inv = 1.0f / fmaxf((float)(lo - start), 1.0f);

  __shared__ float gmean[64];
  gmean[threadIdx.x] = gsum[(size_t)g * 64 + threadIdx.x] * inv;
  __syncthreads();

  __shared__ float hid[32];
  if (threadIdx.x < 32) {
    float a = fcb1[threadIdx.x];
    #pragma unroll
    for (int k = 0; k < 64; ++k) a += gmean[k] * fcw1[k * 32 + threadIdx.x];
    hid[threadIdx.x] = a;
  }
  __syncthreads();

  if (threadIdx.x < 2) {
    float a = fcb2[threadIdx.x];
    #pragma unroll
    for (int k = 0; k < 32; ++k) a += hid[k] * fcw2[k * 2 + threadIdx.x];
    out[g * 2 + threadIdx.x] = a;
  }
}

extern "C" void kernel_launch(void* const* d_in, const int* in_sizes, int n_in,
                              void* d_out, int out_size, void* d_ws, size_t ws_size,
                              hipStream_t stream) {
  const float* x    = (const float*)d_in[0];
  const int*   ei   = (const int*)d_in[1];
  const int*   batch= (const int*)d_in[2];
  const float* W1   = (const float*)d_in[3];
  const float* b1   = (const float*)d_in[4];
  const float* W2   = (const float*)d_in[5];
  const float* b2   = (const float*)d_in[6];
  const float* fcw1 = (const float*)d_in[7];
  const float* fcb1 = (const float*)d_in[8];
  const float* fcw2 = (const float*)d_in[9];
  const float* fcb2 = (const float*)d_in[10];
  float* out = (float*)d_out;

  char* w = (char*)d_ws;
  size_t off = 0;
  auto alloc = [&](size_t bytes) {
    void* p = w + off;
    off += (bytes + 255) & ~(size_t)255;
    return p;
  };
  float*    gsum    = (float*)   alloc((size_t)NUM_GRAPHS * 64 * 4);  // 32 KB
  int*      bcount  = (int*)     alloc((size_t)NB * 4);               // 2 KB (adjacent)
  unsigned* binned  = (unsigned*)alloc((size_t)NB * BCAP * 4);        // 21 MB
  float4*   xs4     = (float4*)  alloc((size_t)N_NODES * 16);         // 2 MB
  unsigned* h1h     = (unsigned*)alloc((size_t)N_NODES * 32);         // 4 MB fp16

  const iv4* src4 = (const iv4*)ei;
  const iv4* dst4 = (const iv4*)(ei + N_EDGES);

  (void)hipMemsetAsync(gsum, 0, (size_t)NUM_GRAPHS * 64 * 4 + (size_t)NB * 4, stream);
  k_binfill<<<N_EDGES / 16384, 1024, 0, stream>>>(src4, dst4, bcount, binned);

  void* args[] = {(void*)&binned, (void*)&bcount, (void*)&x, (void*)&batch,
                  (void*)&W1, (void*)&b1, (void*)&W2, (void*)&b2,
                  (void*)&xs4, (void*)&h1h, (void*)&gsum};
  hipError_t ce = hipLaunchCooperativeKernel((const void*)k_fused, dim3(NB),
                                             dim3(512), args, 0, stream);
  if (ce != hipSuccess) {
    // fallback: proven split pipeline
    k_prep<<<NB, 1024, 0, stream>>>(binned, bcount, x, xs4);
    k_fb3h1<<<NB, 1024, 0, stream>>>(binned, bcount, (const float*)xs4, xs4, W1, b1, h1h);
    k_fb16pool<<<NB, 1024, 0, stream>>>(binned, bcount, h1h, batch, W2, b2, gsum);
  }

  k_fc<<<NUM_GRAPHS, 64, 0, stream>>>(gsum, batch, fcw1, fcb1, fcw2, fcb2, out);
}

// Round 18
// 121.600 us; speedup vs baseline: 3.0816x; 3.0816x over previous
//
#include <hip/hip_runtime.h>
#include <hip/hip_fp16.h>

#define N_NODES 131072
#define N_EDGES 4194304
#define NUM_GRAPHS 128

#define NB 512        // buckets (write-locality-friendly binning)
#define NPB 256       // nodes per bucket
#define BSHIFT 8      // dst>>8 = bucket, dst&255 = local node
#define BCAP 10240    // slots per bucket (mean 8192, sd ~90 -> +22 sigma)
#define GSPAN 8       // max graphs tracked in LDS per bucket (fallback: global)

typedef int iv4 __attribute__((ext_vector_type(4)));  // NT-loadable int4

// ------- bin edges by dst bucket; batch-reserved contiguous runs ---------------
// single-atomic-pass: rank atomic doubles as the histogram.
__global__ __launch_bounds__(1024) void k_binfill(const iv4* __restrict__ src4,
                                                  const iv4* __restrict__ dst4,
                                                  int* __restrict__ bcount,
                                                  unsigned* __restrict__ binned) {
  __shared__ int base_[NB], rank_[NB];
  for (int k = threadIdx.x; k < NB; k += 1024) rank_[k] = 0;
  __syncthreads();
  unsigned pk[16];
  int bk[16], rr[16];
  int q0 = blockIdx.x * 4096 + threadIdx.x;  // int4 index
  #pragma unroll
  for (int i = 0; i < 4; ++i) {
    iv4 sv = __builtin_nontemporal_load(&src4[q0 + i * 1024]);
    iv4 dv = __builtin_nontemporal_load(&dst4[q0 + i * 1024]);
    #pragma unroll
    for (int j = 0; j < 4; ++j) {
      int idx = i * 4 + j;
      int s = sv[j], d = dv[j];
      bk[idx] = d >> BSHIFT;
      pk[idx] = ((unsigned)s << BSHIFT) | (unsigned)(d & (NPB - 1));
      rr[idx] = atomicAdd(&rank_[bk[idx]], 1);
    }
  }
  __syncthreads();
  for (int k = threadIdx.x; k < NB; k += 1024)
    base_[k] = k * BCAP + atomicAdd(&bcount[k], rank_[k]);
  __syncthreads();
  #pragma unroll
  for (int i = 0; i < 16; ++i)
    binned[base_[bk[i]] + rr[i]] = pk[i];   // plain store: L2 merges the scatter
}

// ------- per-bucket degree histogram -> xs = dinv*x (padded float4) ------------
__global__ __launch_bounds__(1024) void k_prep(const unsigned* __restrict__ binned,
                                               const int* __restrict__ bcount,
                                               const float* __restrict__ x,
                                               float4* __restrict__ xs4) {
  __shared__ int dcount[NPB];
  int tid = threadIdx.x;
  if (tid < NPB) dcount[tid] = 0;
  __syncthreads();
  int b = blockIdx.x;
  int s0 = b * BCAP;
  int n = bcount[b];
  for (int e = tid; e < n; e += 1024) {
    unsigned ent = __builtin_nontemporal_load(&binned[s0 + e]);
    atomicAdd(&dcount[ent & (NPB - 1)], 1);
  }
  __syncthreads();
  if (tid < NPB) {
    int node = b * NPB + tid;
    float di = rsqrtf((float)(dcount[tid] + 1));  // +1: self-loop
    xs4[node] = make_float4(di * x[node * 3 + 0], di * x[node * 3 + 1],
                            di * x[node * 3 + 2], 0.f);
  }
}

// ---- fused: local counting sort + gather-agg of xs + W1 proj + relu -> fp16 ---
__global__ __launch_bounds__(1024) void k_sagg3h1(const unsigned* __restrict__ binned,
                                                  const int* __restrict__ bcount,
                                                  const float* __restrict__ xs,
                                                  const float4* __restrict__ xs4,
                                                  const float* __restrict__ W1,
                                                  const float* __restrict__ b1,
                                                  unsigned* __restrict__ h1h) {
  __shared__ int dcount[NPB], cursor[NPB], nbase[NPB];
  __shared__ int wsum[4];
  __shared__ int csrL[BCAP];  // 40 KB, byte offsets (srcn<<4)
  __shared__ float w[48];
  __shared__ float bb[16];
  __shared__ float accS[NPB * 4];
  int tid = threadIdx.x;
  if (tid >= 512 && tid < 560) w[tid - 512] = W1[tid - 512];
  if (tid >= 576 && tid < 592) bb[tid - 576] = b1[tid - 576];
  if (tid < NPB) dcount[tid] = 0;
  __syncthreads();

  int b = blockIdx.x;
  int s0 = b * BCAP;
  int n = bcount[b];
  unsigned ent_r[10];
  #pragma unroll
  for (int j = 0; j < 10; ++j) {
    int e = tid + j * 1024;
    if (e < n) {
      unsigned ent = __builtin_nontemporal_load(&binned[s0 + e]);
      ent_r[j] = ent;
      atomicAdd(&dcount[ent & (NPB - 1)], 1);
    }
  }
  __syncthreads();

  int v = (tid < NPB) ? dcount[tid] : 0;
  {
    int incl = v;
    #pragma unroll
    for (int d = 1; d < 64; d <<= 1) {
      int t = __shfl_up(incl, d);
      if ((tid & 63) >= d) incl += t;
    }
    if (tid < NPB && (tid & 63) == 63) wsum[tid >> 6] = incl;
    __syncthreads();
    if (tid < NPB) {
      int base = 0;
      int wv = tid >> 6;
      for (int w2 = 0; w2 < wv; ++w2) base += wsum[w2];
      int pref = base + incl - v;
      cursor[tid] = pref;
      nbase[tid] = pref;
    }
  }
  __syncthreads();

  #pragma unroll
  for (int j = 0; j < 10; ++j) {
    int e = tid + j * 1024;
    if (e < n) {
      unsigned ent = ent_r[j];
      int pos = atomicAdd(&cursor[ent & (NPB - 1)], 1);
      csrL[pos] = (int)(ent >> BSHIFT) << 4;  // byte offset into xs4
    }
  }
  __syncthreads();

  // gather: 4 lanes/node
  int dl = tid >> 2;
  int q = tid & 3;
  int node = b * NPB + dl;
  int off = nbase[dl];
  int len = dcount[dl];
  const char* xsc = (const char*)xs;
  int qb = q << 2;
  float acc = 0.f;
  #pragma unroll 4
  for (int k = 0; k < len; ++k) {
    int bo = csrL[off + k];                       // LDS broadcast to 4 lanes
    acc += *(const float*)(xsc + bo + qb);        // 4 lanes = 16B row
  }
  accS[tid] = acc;
  __syncthreads();

  float di = rsqrtf((float)(len + 1));
  float4 xself = xs4[node];
  float a0 = di * (accS[dl * 4 + 0] + xself.x);
  float a1 = di * (accS[dl * 4 + 1] + xself.y);
  float a2 = di * (accS[dl * 4 + 2] + xself.z);
  float o[4];
  #pragma unroll
  for (int j = 0; j < 4; ++j) {
    int cc = q * 4 + j;
    float vv = a0 * w[cc] + a1 * w[16 + cc] + a2 * w[32 + cc] + bb[cc];
    o[j] = di * fmaxf(vv, 0.f);
  }
  __half2 p0 = __floats2half2_rn(o[0], o[1]);
  __half2 p1 = __floats2half2_rn(o[2], o[3]);
  uint2 st;
  st.x = *reinterpret_cast<unsigned*>(&p0);
  st.y = *reinterpret_cast<unsigned*>(&p1);
  *(uint2*)(h1h + (size_t)node * 8 + q * 2) = st;
}

// ---- fused: local sort + gather-agg h1 + h2=relu(agg@W2+b2) + graph pool ------
__global__ __launch_bounds__(1024) void k_sagg16pool(const unsigned* __restrict__ binned,
                                                     const int* __restrict__ bcount,
                                                     const unsigned* __restrict__ h1h,
                                                     const int* __restrict__ batch,
                                                     const float* __restrict__ W2,
                                                     const float* __restrict__ b2,
                                                     float* __restrict__ gsum) {
  __shared__ int dcount[NPB], cursor[NPB], nbase[NPB];
  __shared__ int wsum[4];
  __shared__ int csrL[BCAP];         // 40 KB, byte offsets (srcn<<5)
  __shared__ __attribute__((aligned(16))) float aggS[NPB * 16];  // 16 KB
  __shared__ float w2s[1024];        // 4 KB
  __shared__ float b2s[64];
  __shared__ float gacc[GSPAN * 64]; // 2 KB
  int tid = threadIdx.x;
  w2s[tid] = W2[tid];
  if (tid < 64) b2s[tid] = b2[tid];
  if (tid < GSPAN * 64) gacc[tid] = 0.f;
  if (tid < NPB) dcount[tid] = 0;
  __syncthreads();

  int b = blockIdx.x;
  int s0 = b * BCAP;
  int n = bcount[b];
  unsigned ent_r[10];
  #pragma unroll
  for (int j = 0; j < 10; ++j) {
    int e = tid + j * 1024;
    if (e < n) {
      unsigned ent = __builtin_nontemporal_load(&binned[s0 + e]);
      ent_r[j] = ent;
      atomicAdd(&dcount[ent & (NPB - 1)], 1);
    }
  }
  __syncthreads();

  int v = (tid < NPB) ? dcount[tid] : 0;
  {
    int incl = v;
    #pragma unroll
    for (int d = 1; d < 64; d <<= 1) {
      int t = __shfl_up(incl, d);
      if ((tid & 63) >= d) incl += t;
    }
    if (tid < NPB && (tid & 63) == 63) wsum[tid >> 6] = incl;
    __syncthreads();
    if (tid < NPB) {
      int base = 0;
      int wv = tid >> 6;
      for (int w2 = 0; w2 < wv; ++w2) base += wsum[w2];
      int pref = base + incl - v;
      cursor[tid] = pref;
      nbase[tid] = pref;
    }
  }
  __syncthreads();

  #pragma unroll
  for (int j = 0; j < 10; ++j) {
    int e = tid + j * 1024;
    if (e < n) {
      unsigned ent = ent_r[j];
      int pos = atomicAdd(&cursor[ent & (NPB - 1)], 1);
      csrL[pos] = (int)(ent >> BSHIFT) << 5;  // byte offset into h1h rows
    }
  }
  __syncthreads();

  // ---- phase A: gather, 4 lanes/node (uint2 = 8B each) ------------------------
  const char* h1c = (const char*)h1h;
  int dl = tid >> 2;
  int q = tid & 3;
  int qb = q << 3;
  int node = b * NPB + dl;
  int off = nbase[dl];
  int len = dcount[dl];
  float o0 = 0.f, o1 = 0.f, o2 = 0.f, o3 = 0.f;
  #pragma unroll 4
  for (int k = 0; k < len; ++k) {
    int bo = csrL[off + k];                          // LDS broadcast to 4 lanes
    uint2 hv = *(const uint2*)(h1c + bo + qb);       // 4 lanes = 32B row
    __half2 p0 = *reinterpret_cast<const __half2*>(&hv.x);
    __half2 p1 = *reinterpret_cast<const __half2*>(&hv.y);
    o0 += __low2float(p0); o1 += __high2float(p0);
    o2 += __low2float(p1); o3 += __high2float(p1);
  }
  float di = rsqrtf((float)(len + 1));
  uint2 sv = *(const uint2*)(h1h + (size_t)node * 8 + q * 2);
  __half2 s0h = *reinterpret_cast<const __half2*>(&sv.x);
  __half2 s1h = *reinterpret_cast<const __half2*>(&sv.y);
  aggS[dl * 16 + q * 4 + 0] = di * (o0 + __low2float(s0h));
  aggS[dl * 16 + q * 4 + 1] = di * (o1 + __high2float(s0h));
  aggS[dl * 16 + q * 4 + 2] = di * (o2 + __low2float(s1h));
  aggS[dl * 16 + q * 4 + 3] = di * (o3 + __high2float(s1h));
  __syncthreads();

  // ---- phase B: h2 = relu(agg@W2+b2), pool by graph (wave-uniform node) -------
  int c = tid & 63;
  // hoist this thread's W2 column into registers (invariant over node loop)
  float w2r[16];
  #pragma unroll
  for (int k = 0; k < 16; ++k) w2r[k] = w2s[k * 64 + c];
  float bc = b2s[c];

  int slot = tid >> 6;  // 16 waves
  int g0 = batch[b * NPB];
  float racc = 0.f;
  int curli = -1;
  const float4* aggS4 = (const float4*)aggS;
  for (int nloc = slot; nloc < NPB; nloc += 16) {
    int li = batch[b * NPB + nloc] - g0;
    if (li != curli) {
      if (curli >= 0) {
        if (curli < GSPAN) atomicAdd(&gacc[curli * 64 + c], racc);
        else atomicAdd(&gsum[(size_t)(g0 + curli) * 64 + c], racc);
      }
      curli = li;
      racc = 0.f;
    }
    // 4 float4 broadcast reads of the agg row
    float4 a0 = aggS4[nloc * 4 + 0];
    float4 a1 = aggS4[nloc * 4 + 1];
    float4 a2 = aggS4[nloc * 4 + 2];
    float4 a3 = aggS4[nloc * 4 + 3];
    float vv = bc;
    vv += a0.x * w2r[0]  + a0.y * w2r[1]  + a0.z * w2r[2]  + a0.w * w2r[3];
    vv += a1.x * w2r[4]  + a1.y * w2r[5]  + a1.z * w2r[6]  + a1.w * w2r[7];
    vv += a2.x * w2r[8]  + a2.y * w2r[9]  + a2.z * w2r[10] + a2.w * w2r[11];
    vv += a3.x * w2r[12] + a3.y * w2r[13] + a3.z * w2r[14] + a3.w * w2r[15];
    racc += fmaxf(vv, 0.f);
  }
  if (curli >= 0) {
    if (curli < GSPAN) atomicAdd(&gacc[curli * 64 + c], racc);
    else atomicAdd(&gsum[(size_t)(g0 + curli) * 64 + c], racc);
  }
  __syncthreads();

  int span = batch[b * NPB + NPB - 1] - g0 + 1;
  if (span > GSPAN) span = GSPAN;
  for (int li = tid >> 6; li < span; li += 16) {
    atomicAdd(&gsum[(size_t)(g0 + li) * 64 + c], gacc[li * 64 + c]);
  }
}

// ---- final: per-graph mean + FC MLP (64->32->2) --------------------------------
__global__ __launch_bounds__(64) void k_fc(const float* __restrict__ gsum,
                                           const int* __restrict__ batch,
                                           const float* __restrict__ fcw1,
                                           const float* __restrict__ fcb1,
                                           const float* __restrict__ fcw2,
                                           const float* __restrict__ fcb2,
                                           float* __restrict__ out) {
  int g = blockIdx.x;
  int lo = 0, hi = N_NODES;
  while (lo < hi) { int m = (lo + hi) >> 1; if (batch[m] < g) lo = m + 1; else hi = m; }
  int start = lo;
  lo = start; hi = N_NODES;
  while (lo < hi) { int m = (lo + hi) >> 1; if (batch[m] < g + 1) lo = m + 1; else hi = m; }
  float inv = 1.0f / fmaxf((float)(lo - start), 1.0f);

  __shared__ float gmean[64];
  gmean[threadIdx.x] = gsum[(size_t)g * 64 + threadIdx.x] * inv;
  __syncthreads();

  __shared__ float hid[32];
  if (threadIdx.x < 32) {
    float a = fcb1[threadIdx.x];
    #pragma unroll
    for (int k = 0; k < 64; ++k) a += gmean[k] * fcw1[k * 32 + threadIdx.x];
    hid[threadIdx.x] = a;
  }
  __syncthreads();

  if (threadIdx.x < 2) {
    float a = fcb2[threadIdx.x];
    #pragma unroll
    for (int k = 0; k < 32; ++k) a += hid[k] * fcw2[k * 2 + threadIdx.x];
    out[g * 2 + threadIdx.x] = a;
  }
}

extern "C" void kernel_launch(void* const* d_in, const int* in_sizes, int n_in,
                              void* d_out, int out_size, void* d_ws, size_t ws_size,
                              hipStream_t stream) {
  const float* x    = (const float*)d_in[0];
  const int*   ei   = (const int*)d_in[1];
  const int*   batch= (const int*)d_in[2];
  const float* W1   = (const float*)d_in[3];
  const float* b1   = (const float*)d_in[4];
  const float* W2   = (const float*)d_in[5];
  const float* b2   = (const float*)d_in[6];
  const float* fcw1 = (const float*)d_in[7];
  const float* fcb1 = (const float*)d_in[8];
  const float* fcw2 = (const float*)d_in[9];
  const float* fcb2 = (const float*)d_in[10];
  float* out = (float*)d_out;

  char* w = (char*)d_ws;
  size_t off = 0;
  auto alloc = [&](size_t bytes) {
    void* p = w + off;
    off += (bytes + 255) & ~(size_t)255;
    return p;
  };
  float*    gsum    = (float*)   alloc((size_t)NUM_GRAPHS * 64 * 4);  // 32 KB
  int*      bcount  = (int*)     alloc((size_t)NB * 4);               // 2 KB (adjacent)
  unsigned* binned  = (unsigned*)alloc((size_t)NB * BCAP * 4);        // 21 MB
  float4*   xs4     = (float4*)  alloc((size_t)N_NODES * 16);         // 2 MB
  unsigned* h1h     = (unsigned*)alloc((size_t)N_NODES * 32);         // 4 MB fp16

  const iv4* src4 = (const iv4*)ei;
  const iv4* dst4 = (const iv4*)(ei + N_EDGES);

  // one memset clears gsum + bcount (adjacent allocations)
  (void)hipMemsetAsync(gsum, 0, (size_t)NUM_GRAPHS * 64 * 4 + (size_t)NB * 4, stream);
  k_binfill<<<N_EDGES / 16384, 1024, 0, stream>>>(src4, dst4, bcount, binned);
  k_prep<<<NB, 1024, 0, stream>>>(binned, bcount, x, xs4);
  k_sagg3h1<<<NB, 1024, 0, stream>>>(binned, bcount, (const float*)xs4, xs4, W1, b1, h1h);
  k_sagg16pool<<<NB, 1024, 0, stream>>>(binned, bcount, h1h, batch, W2, b2, gsum);
  k_fc<<<NUM_GRAPHS, 64, 0, stream>>>(gsum, batch, fcw1, fcb1, fcw2, fcb2, out);
}